// Round 1
// baseline (2802.814 us; speedup 1.0000x reference)
//
#include <hip/hip_runtime.h>
#include <hip/hip_bf16.h>

#define F_IN 256
#define HID  64
#define CLS  40
#define EPS  1e-8f

// -------------------- dtype detection (int64 vs int32 edge_index) -----------
__global__ void detect_kernel(const int* __restrict__ raw, int* __restrict__ flag) {
    int c = threadIdx.x;                  // one wave
    int w = raw[2 * c + 1];               // odd int32 words
    unsigned long long b = __ballot(w != 0);
    if (c == 0) *flag = (b == 0ULL) ? 1 : 0;   // all zero -> int64 layout
}

__global__ void init_deg_kernel(int* __restrict__ deg, int n) {
    int v = blockIdx.x * blockDim.x + threadIdx.x;
    if (v < n) deg[v] = 1;                // self-loop
}

__global__ void convert_kernel(const void* __restrict__ raw, const int* __restrict__ flag,
                               int* __restrict__ src, int* __restrict__ dst,
                               int* __restrict__ deg, int E) {
    int e = blockIdx.x * blockDim.x + threadIdx.x;
    if (e >= E) return;
    int s, d;
    if (*flag) {
        const long long* r = (const long long*)raw;
        s = (int)r[e]; d = (int)r[E + e];
    } else {
        const int* r = (const int*)raw;
        s = r[e]; d = r[E + e];
    }
    src[e] = s; dst[e] = d;
    atomicAdd(&deg[d], 1);
}

__global__ void dinv_kernel(const int* __restrict__ deg, float* __restrict__ dinv, int n) {
    int v = blockIdx.x * blockDim.x + threadIdx.x;
    if (v < n) dinv[v] = rsqrtf((float)deg[v]);   // deg >= 1 always
}

// -------------------- layer 1 GEMM: xw = x @ W1 ; acc1 init = xw*dinv^2 -----
// block 256 = 16 nodes x 16 threads (4 channels each)
__global__ void gemm1_kernel(const float* __restrict__ x, const float* __restrict__ W1,
                             const float* __restrict__ dinv,
                             float* __restrict__ xw, float* __restrict__ acc1, int n) {
    __shared__ float xs[16 * 260];        // stride 260 -> conflict-free
    int node0 = blockIdx.x * 16;
    for (int i = threadIdx.x; i < 16 * 64; i += 256) {   // 1024 float4 loads
        int r  = i >> 6;
        int c4 = (i & 63) << 2;
        int node = node0 + r;
        float4 v = (node < n) ? *(const float4*)(x + (size_t)node * F_IN + c4)
                              : make_float4(0.f, 0.f, 0.f, 0.f);
        *(float4*)(&xs[r * 260 + c4]) = v;
    }
    __syncthreads();
    int nl = threadIdx.x >> 4;            // 0..15
    int cq = (threadIdx.x & 15) << 2;     // 0,4,...,60
    float a0 = 0.f, a1 = 0.f, a2 = 0.f, a3 = 0.f;
    const float* xr = &xs[nl * 260];
    #pragma unroll 4
    for (int k = 0; k < F_IN; ++k) {
        float xv = xr[k];
        float4 w = *(const float4*)(W1 + k * HID + cq);
        a0 += xv * w.x; a1 += xv * w.y; a2 += xv * w.z; a3 += xv * w.w;
    }
    int node = node0 + nl;
    if (node < n) {
        float di = dinv[node];
        float sl = di * di;
        size_t base = (size_t)node * HID + cq;
        xw[base + 0] = a0; xw[base + 1] = a1; xw[base + 2] = a2; xw[base + 3] = a3;
        acc1[base + 0] = a0 * sl; acc1[base + 1] = a1 * sl;
        acc1[base + 2] = a2 * sl; acc1[base + 3] = a3 * sl;
    }
}

// -------------------- layer 1 scatter: acc1[d] += xw[s] * dinv[s]*dinv[d] ---
// thread = (edge, 4-channel quad): 16 threads/edge
__global__ void scatter1_kernel(const int* __restrict__ src, const int* __restrict__ dst,
                                const float* __restrict__ dinv, const float* __restrict__ xw,
                                float* __restrict__ acc1, int E) {
    int t = blockIdx.x * blockDim.x + threadIdx.x;
    int e = t >> 4;
    if (e >= E) return;
    int c4 = (t & 15) << 2;
    int s = src[e], d = dst[e];
    float nrm = dinv[s] * dinv[d];
    float4 v = *(const float4*)(xw + (size_t)s * HID + c4);
    float* out = acc1 + (size_t)d * HID + c4;
    unsafeAtomicAdd(out + 0, v.x * nrm);
    unsafeAtomicAdd(out + 1, v.y * nrm);
    unsafeAtomicAdd(out + 2, v.z * nrm);
    unsafeAtomicAdd(out + 3, v.w * nrm);
}

// ------------- layer 2 GEMM: hw = relu(acc1+b1) @ W2 ; xout init = hw*dinv^2
// block 256 = 4 node-groups of 64 lanes; lanes c<40 active for output
__global__ void gemm2_kernel(const float* __restrict__ acc1, const float* __restrict__ b1,
                             const float* __restrict__ W2, const float* __restrict__ dinv,
                             float* __restrict__ hw, float* __restrict__ xout, int n) {
    int nl = threadIdx.x >> 6;
    int c  = threadIdx.x & 63;
    int node = blockIdx.x * 4 + nl;
    if (node >= n) return;
    float acc = 0.f;
    const float* hrow = acc1 + (size_t)node * HID;
    #pragma unroll 8
    for (int k = 0; k < HID; ++k) {
        float hk = fmaxf(hrow[k] + b1[k], 0.f);      // broadcast loads
        if (c < CLS) acc += hk * W2[k * CLS + c];
    }
    if (c < CLS) {
        float di = dinv[node];
        float sl = di * di;
        size_t base = (size_t)node * CLS + c;
        hw[base]   = acc;
        xout[base] = acc * sl;
    }
}

// -------------------- layer 2 scatter --------------------------------------
__global__ void scatter2_kernel(const int* __restrict__ src, const int* __restrict__ dst,
                                const float* __restrict__ dinv, const float* __restrict__ hw,
                                float* __restrict__ xout, int E) {
    int t = blockIdx.x * blockDim.x + threadIdx.x;
    int e = t >> 4;
    if (e >= E) return;
    int c4 = (t & 15) << 2;
    if (c4 >= CLS) return;
    int s = src[e], d = dst[e];
    float nrm = dinv[s] * dinv[d];
    float4 v = *(const float4*)(hw + (size_t)s * CLS + c4);
    float* out = xout + (size_t)d * CLS + c4;
    unsafeAtomicAdd(out + 0, v.x * nrm);
    unsafeAtomicAdd(out + 1, v.y * nrm);
    unsafeAtomicAdd(out + 2, v.z * nrm);
    unsafeAtomicAdd(out + 3, v.w * nrm);
}

// ------------- finalize: +b2, log_softmax, softmax, rnorm -------------------
// wave per node, lanes 0..39 active
__global__ void finalize_kernel(const float* __restrict__ b2, float* __restrict__ xout,
                                float* __restrict__ lsm, float* __restrict__ sm,
                                float* __restrict__ rnorm, int n) {
    int t = blockIdx.x * blockDim.x + threadIdx.x;
    int node = t >> 6;
    int c = t & 63;
    if (node >= n) return;
    float raw = 0.f;
    size_t base = (size_t)node * CLS + c;
    if (c < CLS) raw = xout[base] + b2[c];
    float m = (c < CLS) ? raw : -3.0e38f;
    #pragma unroll
    for (int o = 32; o > 0; o >>= 1) m = fmaxf(m, __shfl_xor(m, o));
    float ex = (c < CLS) ? expf(raw - m) : 0.f;
    float ssum = ex;
    #pragma unroll
    for (int o = 32; o > 0; o >>= 1) ssum += __shfl_xor(ssum, o);
    float sq = (c < CLS) ? raw * raw : 0.f;
    #pragma unroll
    for (int o = 32; o > 0; o >>= 1) sq += __shfl_xor(sq, o);
    if (c < CLS) {
        xout[base] = raw;
        float lse = m + logf(ssum);
        lsm[base] = raw - lse;
        sm[base]  = ex / ssum;
    }
    if (c == 0) rnorm[node] = 1.0f / fmaxf(sqrtf(sq), EPS);
}

// ------------- per-edge cosine dissimilarity + gnn_edge ---------------------
__global__ void edge_kernel(const int* __restrict__ src, const int* __restrict__ dst,
                            const float* __restrict__ ew, const float* __restrict__ xout,
                            const float* __restrict__ rnorm,
                            float* __restrict__ cos_out, float* __restrict__ gnn_out, int E) {
    int e = blockIdx.x * blockDim.x + threadIdx.x;
    if (e >= E) return;
    int s = src[e], d = dst[e];
    const float4* a = (const float4*)(xout + (size_t)s * CLS);
    const float4* b = (const float4*)(xout + (size_t)d * CLS);
    float dot = 0.f;
    #pragma unroll
    for (int i = 0; i < CLS / 4; ++i) {
        float4 av = a[i], bv = b[i];
        dot += av.x * bv.x + av.y * bv.y + av.z * bv.z + av.w * bv.w;
    }
    cos_out[e] = 1.0f - dot * rnorm[s] * rnorm[d];
    gnn_out[e] = (ew[e] > 0.5f) ? 1.0f : -1.0f;
}

// ---------------------------------------------------------------------------
extern "C" void kernel_launch(void* const* d_in, const int* in_sizes, int n_in,
                              void* d_out, int out_size, void* d_ws, size_t ws_size,
                              hipStream_t stream) {
    const float* x   = (const float*)d_in[0];
    const void*  ei  = d_in[1];
    const float* ew  = (const float*)d_in[2];
    const float* W1  = (const float*)d_in[3];
    const float* b1  = (const float*)d_in[4];
    const float* W2  = (const float*)d_in[5];
    const float* b2  = (const float*)d_in[6];

    const int n = in_sizes[0] / F_IN;        // 50000
    const int E = in_sizes[2];               // 1600000

    // output segments (return order)
    float* lsm  = (float*)d_out;                                   // [n*CLS]
    float* xout = lsm + (size_t)n * CLS;                           // [n*CLS]
    float* cosO = xout + (size_t)n * CLS;                          // [E]
    float* gnnO = cosO + E;                                        // [E]
    float* smO  = gnnO + E;                                        // [n*CLS]

    // workspace layout (256B aligned)
    char* w = (char*)d_ws;
    auto alloc = [&](size_t bytes) {
        char* p = w;
        w += (bytes + 255) & ~(size_t)255;
        return p;
    };
    int*   src32 = (int*)  alloc((size_t)E * 4);
    int*   dst32 = (int*)  alloc((size_t)E * 4);
    int*   deg   = (int*)  alloc((size_t)n * 4);
    float* dinv  = (float*)alloc((size_t)n * 4);
    float* xw    = (float*)alloc((size_t)n * HID * 4);
    float* acc1  = (float*)alloc((size_t)n * HID * 4);
    float* hw    = (float*)alloc((size_t)n * CLS * 4);
    float* rnorm = (float*)alloc((size_t)n * 4);
    int*   flag  = (int*)  alloc(64);

    detect_kernel<<<1, 64, 0, stream>>>((const int*)ei, flag);
    init_deg_kernel<<<(n + 255) / 256, 256, 0, stream>>>(deg, n);
    convert_kernel<<<(E + 255) / 256, 256, 0, stream>>>(ei, flag, src32, dst32, deg, E);
    dinv_kernel<<<(n + 255) / 256, 256, 0, stream>>>(deg, dinv, n);
    gemm1_kernel<<<(n + 15) / 16, 256, 0, stream>>>(x, W1, dinv, xw, acc1, n);
    scatter1_kernel<<<((size_t)E * 16 + 255) / 256, 256, 0, stream>>>(src32, dst32, dinv, xw, acc1, E);
    gemm2_kernel<<<(n + 3) / 4, 256, 0, stream>>>(acc1, b1, W2, dinv, hw, xout, n);
    scatter2_kernel<<<((size_t)E * 16 + 255) / 256, 256, 0, stream>>>(src32, dst32, dinv, hw, xout, E);
    finalize_kernel<<<((size_t)n * 64 + 255) / 256, 256, 0, stream>>>(b2, xout, lsm, smO, rnorm, n);
    edge_kernel<<<(E + 255) / 256, 256, 0, stream>>>(src32, dst32, ew, xout, rnorm, cosO, gnnO, E);
}

// Round 2
// 800.181 us; speedup vs baseline: 3.5027x; 3.5027x over previous
//
#include <hip/hip_runtime.h>
#include <hip/hip_bf16.h>

#define F_IN 256
#define HID  64
#define CLS  40
#define EPS  1e-8f

// -------------------- dtype detection (int64 vs int32 edge_index) -----------
__global__ void detect_kernel(const int* __restrict__ raw, int* __restrict__ flag) {
    int c = threadIdx.x;                  // one wave
    int w = raw[2 * c + 1];               // odd int32 words
    unsigned long long b = __ballot(w != 0);
    if (c == 0) *flag = (b == 0ULL) ? 1 : 0;   // all zero -> int64 layout
}

__global__ void init_deg_kernel(int* __restrict__ deg, int n) {
    int v = blockIdx.x * blockDim.x + threadIdx.x;
    if (v < n) deg[v] = 1;                // self-loop
}

__global__ void convert_kernel(const void* __restrict__ raw, const int* __restrict__ flag,
                               int* __restrict__ src, int* __restrict__ dst,
                               int* __restrict__ deg, int E) {
    int e = blockIdx.x * blockDim.x + threadIdx.x;
    if (e >= E) return;
    int s, d;
    if (*flag) {
        const long long* r = (const long long*)raw;
        s = (int)r[e]; d = (int)r[E + e];
    } else {
        const int* r = (const int*)raw;
        s = r[e]; d = r[E + e];
    }
    src[e] = s; dst[e] = d;
    atomicAdd(&deg[d], 1);
}

__global__ void dinv_kernel(const int* __restrict__ deg, float* __restrict__ dinv, int n) {
    int v = blockIdx.x * blockDim.x + threadIdx.x;
    if (v < n) dinv[v] = rsqrtf((float)deg[v]);   // deg >= 1 always
}

// ---------- rowptr: exclusive scan of per-node edge counts (deg-1) ----------
// single block of 1024; each thread scans a contiguous chunk
__global__ void scan_kernel(const int* __restrict__ deg, int* __restrict__ rowptr,
                            int* __restrict__ cursor, int n) {
    __shared__ int partial[1024];
    int t = threadIdx.x;
    int chunk = (n + 1023) / 1024;
    int start = t * chunk;
    int end   = min(start + chunk, n);
    int sum = 0;
    for (int i = start; i < end; ++i) sum += deg[i] - 1;
    partial[t] = sum;
    __syncthreads();
    for (int o = 1; o < 1024; o <<= 1) {          // inclusive Hillis-Steele
        int v = (t >= o) ? partial[t - o] : 0;
        __syncthreads();
        partial[t] += v;
        __syncthreads();
    }
    int off = (t == 0) ? 0 : partial[t - 1];
    for (int i = start; i < end; ++i) {
        rowptr[i] = off;
        cursor[i] = off;
        off += deg[i] - 1;
    }
    if (t == 1023) rowptr[n] = partial[1023];     // == E
}

// ---------- fill CSR: csr[pos] = src, grouped by dst ------------------------
__global__ void fill_kernel(const int* __restrict__ src, const int* __restrict__ dst,
                            int* __restrict__ cursor, int* __restrict__ csr, int E) {
    int e = blockIdx.x * blockDim.x + threadIdx.x;
    if (e >= E) return;
    int pos = atomicAdd(&cursor[dst[e]], 1);
    csr[pos] = src[e];
}

// -------------------- layer 1 GEMM: xws = (x @ W1) * dinv[node] -------------
// block 256 = 16 nodes x 16 threads (4 channels each)
__global__ void gemm1_kernel(const float* __restrict__ x, const float* __restrict__ W1,
                             const float* __restrict__ dinv,
                             float* __restrict__ xws, int n) {
    __shared__ float xs[16 * 260];        // stride 260 -> conflict-free
    int node0 = blockIdx.x * 16;
    for (int i = threadIdx.x; i < 16 * 64; i += 256) {   // 1024 float4 loads
        int r  = i >> 6;
        int c4 = (i & 63) << 2;
        int node = node0 + r;
        float4 v = (node < n) ? *(const float4*)(x + (size_t)node * F_IN + c4)
                              : make_float4(0.f, 0.f, 0.f, 0.f);
        *(float4*)(&xs[r * 260 + c4]) = v;
    }
    __syncthreads();
    int nl = threadIdx.x >> 4;            // 0..15
    int cq = (threadIdx.x & 15) << 2;     // 0,4,...,60
    float a0 = 0.f, a1 = 0.f, a2 = 0.f, a3 = 0.f;
    const float* xr = &xs[nl * 260];
    #pragma unroll 4
    for (int k = 0; k < F_IN; ++k) {
        float xv = xr[k];
        float4 w = *(const float4*)(W1 + k * HID + cq);
        a0 += xv * w.x; a1 += xv * w.y; a2 += xv * w.z; a3 += xv * w.w;
    }
    int node = node0 + nl;
    if (node < n) {
        float di = dinv[node];
        size_t base = (size_t)node * HID + cq;
        xws[base + 0] = a0 * di; xws[base + 1] = a1 * di;
        xws[base + 2] = a2 * di; xws[base + 3] = a3 * di;
    }
}

// ---------- layer 1 gather: h = relu(dinv[d]*(xws[d] + sum_s xws[s]) + b1) --
// one wave per node, lane = channel (64 == HID)
__global__ void gather1_kernel(const int* __restrict__ rowptr, const int* __restrict__ csr,
                               const float* __restrict__ xws, const float* __restrict__ dinv,
                               const float* __restrict__ b1, float* __restrict__ h, int n) {
    int wv = (blockIdx.x * blockDim.x + threadIdx.x) >> 6;
    int c  = threadIdx.x & 63;
    if (wv >= n) return;
    int beg = rowptr[wv], endp = rowptr[wv + 1];
    float acc = xws[(size_t)wv * HID + c];            // self-loop term
    int j = beg;
    for (; j + 4 <= endp; j += 4) {
        int s0 = csr[j], s1 = csr[j + 1], s2 = csr[j + 2], s3 = csr[j + 3];
        acc += xws[(size_t)s0 * HID + c] + xws[(size_t)s1 * HID + c]
             + xws[(size_t)s2 * HID + c] + xws[(size_t)s3 * HID + c];
    }
    for (; j < endp; ++j) acc += xws[(size_t)csr[j] * HID + c];
    float v = acc * dinv[wv] + b1[c];
    h[(size_t)wv * HID + c] = fmaxf(v, 0.f);
}

// ------------- layer 2 GEMM: hws = (h @ W2) * dinv[node] --------------------
// block 256 = 4 node-groups of 64 lanes; lanes c<40 produce output
__global__ void gemm2_kernel(const float* __restrict__ h, const float* __restrict__ W2,
                             const float* __restrict__ dinv,
                             float* __restrict__ hws, int n) {
    int nl = threadIdx.x >> 6;
    int c  = threadIdx.x & 63;
    int node = blockIdx.x * 4 + nl;
    if (node >= n) return;
    float acc = 0.f;
    const float* hrow = h + (size_t)node * HID;
    #pragma unroll 8
    for (int k = 0; k < HID; ++k) {
        float hk = hrow[k];                          // broadcast loads
        if (c < CLS) acc += hk * W2[k * CLS + c];
    }
    if (c < CLS) hws[(size_t)node * CLS + c] = acc * dinv[node];
}

// ---------- layer 2 gather fused with finalize ------------------------------
// xout = dinv[d]*(hws[d] + sum hws[s]) + b2 ; then log_softmax/softmax/rnorm
__global__ void gather2_fin_kernel(const int* __restrict__ rowptr, const int* __restrict__ csr,
                                   const float* __restrict__ hws, const float* __restrict__ dinv,
                                   const float* __restrict__ b2,
                                   float* __restrict__ xout, float* __restrict__ lsm,
                                   float* __restrict__ sm, float* __restrict__ rnorm, int n) {
    int wv = (blockIdx.x * blockDim.x + threadIdx.x) >> 6;
    int c  = threadIdx.x & 63;
    if (wv >= n) return;
    int beg = rowptr[wv], endp = rowptr[wv + 1];
    float acc = 0.f;
    if (c < CLS) acc = hws[(size_t)wv * CLS + c];     // self-loop term
    int j = beg;
    for (; j + 4 <= endp; j += 4) {
        int s0 = csr[j], s1 = csr[j + 1], s2 = csr[j + 2], s3 = csr[j + 3];
        if (c < CLS)
            acc += hws[(size_t)s0 * CLS + c] + hws[(size_t)s1 * CLS + c]
                 + hws[(size_t)s2 * CLS + c] + hws[(size_t)s3 * CLS + c];
    }
    for (; j < endp; ++j) {
        int s = csr[j];
        if (c < CLS) acc += hws[(size_t)s * CLS + c];
    }
    float raw = 0.f;
    if (c < CLS) raw = acc * dinv[wv] + b2[c];
    float m = (c < CLS) ? raw : -3.0e38f;
    #pragma unroll
    for (int o = 32; o > 0; o >>= 1) m = fmaxf(m, __shfl_xor(m, o));
    float ex = (c < CLS) ? __expf(raw - m) : 0.f;
    float ssum = ex;
    #pragma unroll
    for (int o = 32; o > 0; o >>= 1) ssum += __shfl_xor(ssum, o);
    float sq = (c < CLS) ? raw * raw : 0.f;
    #pragma unroll
    for (int o = 32; o > 0; o >>= 1) sq += __shfl_xor(sq, o);
    size_t base = (size_t)wv * CLS + c;
    if (c < CLS) {
        xout[base] = raw;
        float lse = m + __logf(ssum);
        lsm[base] = raw - lse;
        sm[base]  = ex / ssum;
    }
    if (c == 0) rnorm[wv] = 1.0f / fmaxf(sqrtf(sq), EPS);
}

// ------------- per-edge cosine dissimilarity + gnn_edge ---------------------
__global__ void edge_kernel(const int* __restrict__ src, const int* __restrict__ dst,
                            const float* __restrict__ ew, const float* __restrict__ xout,
                            const float* __restrict__ rnorm,
                            float* __restrict__ cos_out, float* __restrict__ gnn_out, int E) {
    int e = blockIdx.x * blockDim.x + threadIdx.x;
    if (e >= E) return;
    int s = src[e], d = dst[e];
    const float4* a = (const float4*)(xout + (size_t)s * CLS);
    const float4* b = (const float4*)(xout + (size_t)d * CLS);
    float dot = 0.f;
    #pragma unroll
    for (int i = 0; i < CLS / 4; ++i) {
        float4 av = a[i], bv = b[i];
        dot += av.x * bv.x + av.y * bv.y + av.z * bv.z + av.w * bv.w;
    }
    cos_out[e] = 1.0f - dot * rnorm[s] * rnorm[d];
    gnn_out[e] = (ew[e] > 0.5f) ? 1.0f : -1.0f;
}

// ---------------------------------------------------------------------------
extern "C" void kernel_launch(void* const* d_in, const int* in_sizes, int n_in,
                              void* d_out, int out_size, void* d_ws, size_t ws_size,
                              hipStream_t stream) {
    const float* x   = (const float*)d_in[0];
    const void*  ei  = d_in[1];
    const float* ew  = (const float*)d_in[2];
    const float* W1  = (const float*)d_in[3];
    const float* b1  = (const float*)d_in[4];
    const float* W2  = (const float*)d_in[5];
    const float* b2  = (const float*)d_in[6];

    const int n = in_sizes[0] / F_IN;        // 50000
    const int E = in_sizes[2];               // 1600000

    // output segments (return order)
    float* lsm  = (float*)d_out;                                   // [n*CLS]
    float* xout = lsm + (size_t)n * CLS;                           // [n*CLS]
    float* cosO = xout + (size_t)n * CLS;                          // [E]
    float* gnnO = cosO + E;                                        // [E]
    float* smO  = gnnO + E;                                        // [n*CLS]

    // workspace layout (256B aligned)
    char* w = (char*)d_ws;
    auto alloc = [&](size_t bytes) {
        char* p = w;
        w += (bytes + 255) & ~(size_t)255;
        return p;
    };
    int*   src32  = (int*)  alloc((size_t)E * 4);
    int*   dst32  = (int*)  alloc((size_t)E * 4);
    int*   csr    = (int*)  alloc((size_t)E * 4);
    int*   deg    = (int*)  alloc((size_t)n * 4);
    int*   rowptr = (int*)  alloc(((size_t)n + 1) * 4);
    int*   cursor = (int*)  alloc((size_t)n * 4);
    float* dinv   = (float*)alloc((size_t)n * 4);
    float* xws    = (float*)alloc((size_t)n * HID * 4);
    float* h      = (float*)alloc((size_t)n * HID * 4);
    float* hws    = (float*)alloc((size_t)n * CLS * 4);
    float* rnorm  = (float*)alloc((size_t)n * 4);
    int*   flag   = (int*)  alloc(64);

    detect_kernel<<<1, 64, 0, stream>>>((const int*)ei, flag);
    init_deg_kernel<<<(n + 255) / 256, 256, 0, stream>>>(deg, n);
    convert_kernel<<<(E + 255) / 256, 256, 0, stream>>>(ei, flag, src32, dst32, deg, E);
    dinv_kernel<<<(n + 255) / 256, 256, 0, stream>>>(deg, dinv, n);
    scan_kernel<<<1, 1024, 0, stream>>>(deg, rowptr, cursor, n);
    fill_kernel<<<(E + 255) / 256, 256, 0, stream>>>(src32, dst32, cursor, csr, E);
    gemm1_kernel<<<(n + 15) / 16, 256, 0, stream>>>(x, W1, dinv, xws, n);
    gather1_kernel<<<((size_t)n * 64 + 255) / 256, 256, 0, stream>>>(rowptr, csr, xws, dinv, b1, h, n);
    gemm2_kernel<<<(n + 3) / 4, 256, 0, stream>>>(h, W2, dinv, hws, n);
    gather2_fin_kernel<<<((size_t)n * 64 + 255) / 256, 256, 0, stream>>>(rowptr, csr, hws, dinv, b2,
                                                                         xout, lsm, smO, rnorm, n);
    edge_kernel<<<(E + 255) / 256, 256, 0, stream>>>(src32, dst32, ew, xout, rnorm, cosO, gnnO, E);
}

// Round 3
// 696.992 us; speedup vs baseline: 4.0213x; 1.1480x over previous
//
#include <hip/hip_runtime.h>
#include <hip/hip_bf16.h>

#define F_IN 256
#define HID  64
#define CLS  40
#define EPS  1e-8f

typedef unsigned short ushort_t;
typedef unsigned int   uint_t;

__device__ __forceinline__ float bf2f(ushort_t u) {
    union { uint_t i; float f; } v; v.i = ((uint_t)u) << 16; return v.f;
}
__device__ __forceinline__ ushort_t f2bf(float f) {
    union { float f; uint_t i; } v; v.f = f;
    uint_t r = v.i + 0x7fff + ((v.i >> 16) & 1);          // RNE
    return (ushort_t)(r >> 16);
}
__device__ __forceinline__ float blo(uint_t p) {
    union { uint_t i; float f; } v; v.i = p << 16; return v.f;
}
__device__ __forceinline__ float bhi(uint_t p) {
    union { uint_t i; float f; } v; v.i = p & 0xffff0000u; return v.f;
}

// -------------------- dtype detection (int64 vs int32 edge_index) -----------
__global__ void detect_kernel(const int* __restrict__ raw, int* __restrict__ flag) {
    int c = threadIdx.x;                  // one wave
    int w = raw[2 * c + 1];               // odd int32 words
    unsigned long long b = __ballot(w != 0);
    if (c == 0) *flag = (b == 0ULL) ? 1 : 0;   // all zero -> int64 layout
}

__global__ void init_deg_kernel(int* __restrict__ deg, int n) {
    int v = blockIdx.x * blockDim.x + threadIdx.x;
    if (v < n) deg[v] = 1;                // self-loop
}

__global__ void convert_kernel(const void* __restrict__ raw, const int* __restrict__ flag,
                               ushort_t* __restrict__ src, ushort_t* __restrict__ dst,
                               int* __restrict__ deg, int E) {
    int e = blockIdx.x * blockDim.x + threadIdx.x;
    if (e >= E) return;
    int s, d;
    if (*flag) {
        const long long* r = (const long long*)raw;
        s = (int)r[e]; d = (int)r[E + e];
    } else {
        const int* r = (const int*)raw;
        s = r[e]; d = r[E + e];
    }
    src[e] = (ushort_t)s; dst[e] = (ushort_t)d;
    atomicAdd(&deg[d], 1);
}

__global__ void dinv_kernel(const int* __restrict__ deg, float* __restrict__ dinv, int n) {
    int v = blockIdx.x * blockDim.x + threadIdx.x;
    if (v < n) dinv[v] = rsqrtf((float)deg[v]);   // deg >= 1 always
}

// ---------- rowptr: exclusive scan of per-node edge counts (deg-1) ----------
__global__ void scan_kernel(const int* __restrict__ deg, int* __restrict__ rowptr,
                            int* __restrict__ cursor, int n) {
    __shared__ int partial[1024];
    int t = threadIdx.x;
    int chunk = (n + 1023) / 1024;
    int start = t * chunk;
    int end   = min(start + chunk, n);
    int sum = 0;
    for (int i = start; i < end; ++i) sum += deg[i] - 1;
    partial[t] = sum;
    __syncthreads();
    for (int o = 1; o < 1024; o <<= 1) {          // inclusive Hillis-Steele
        int v = (t >= o) ? partial[t - o] : 0;
        __syncthreads();
        partial[t] += v;
        __syncthreads();
    }
    int off = (t == 0) ? 0 : partial[t - 1];
    for (int i = start; i < end; ++i) {
        rowptr[i] = off;
        cursor[i] = off;
        off += deg[i] - 1;
    }
    if (t == 1023) rowptr[n] = partial[1023];     // == E
}

// ---------- fill CSR (ushort entries): csr[pos] = src, grouped by dst -------
__global__ void fill_kernel(const ushort_t* __restrict__ src, const ushort_t* __restrict__ dst,
                            int* __restrict__ cursor, ushort_t* __restrict__ csr, int E) {
    int e = blockIdx.x * blockDim.x + threadIdx.x;
    if (e >= E) return;
    int pos = atomicAdd(&cursor[dst[e]], 1);
    csr[pos] = src[e];
}

// -------------------- layer 1 GEMM: xws = bf16((x @ W1) * dinv[node]) -------
// block 256 = 16 nodes x 16 threads (4 channels each)
__global__ void gemm1_kernel(const float* __restrict__ x, const float* __restrict__ W1,
                             const float* __restrict__ dinv,
                             ushort_t* __restrict__ xws, int n) {
    __shared__ float xs[16 * 260];        // stride 260 -> conflict-free
    int node0 = blockIdx.x * 16;
    for (int i = threadIdx.x; i < 16 * 64; i += 256) {   // 1024 float4 loads
        int r  = i >> 6;
        int c4 = (i & 63) << 2;
        int node = node0 + r;
        float4 v = (node < n) ? *(const float4*)(x + (size_t)node * F_IN + c4)
                              : make_float4(0.f, 0.f, 0.f, 0.f);
        *(float4*)(&xs[r * 260 + c4]) = v;
    }
    __syncthreads();
    int nl = threadIdx.x >> 4;            // 0..15
    int cq = (threadIdx.x & 15) << 2;     // 0,4,...,60
    float a0 = 0.f, a1 = 0.f, a2 = 0.f, a3 = 0.f;
    const float* xr = &xs[nl * 260];
    #pragma unroll 4
    for (int k = 0; k < F_IN; ++k) {
        float xv = xr[k];
        float4 w = *(const float4*)(W1 + k * HID + cq);
        a0 += xv * w.x; a1 += xv * w.y; a2 += xv * w.z; a3 += xv * w.w;
    }
    int node = node0 + nl;
    if (node < n) {
        float di = dinv[node];
        uint2 p;
        p.x = (uint_t)f2bf(a0 * di) | ((uint_t)f2bf(a1 * di) << 16);
        p.y = (uint_t)f2bf(a2 * di) | ((uint_t)f2bf(a3 * di) << 16);
        *(uint2*)(xws + (size_t)node * HID + cq) = p;     // 8B aligned
    }
}

// ---- fused: gather1 (h = relu(dinv*(sum)+b1)) + gemm2 (hws = h@W2 * dinv) --
// one wave per node; 4 waves/block; h row staged in LDS for the 64->40 matmul
__global__ void gather1_gemm2_kernel(const int* __restrict__ rowptr,
                                     const ushort_t* __restrict__ csr,
                                     const ushort_t* __restrict__ xws,
                                     const float* __restrict__ dinv,
                                     const float* __restrict__ b1,
                                     const float* __restrict__ W2,
                                     ushort_t* __restrict__ hws, int n) {
    __shared__ float hbuf[4][72];
    int wave = threadIdx.x >> 6;
    int c    = threadIdx.x & 63;
    int wv   = (blockIdx.x * blockDim.x + threadIdx.x) >> 6;
    bool active = wv < n;
    int beg = 0, endp = 0;
    float acc = 0.f, di = 0.f;
    if (active) {
        beg = rowptr[wv]; endp = rowptr[wv + 1];
        di  = dinv[wv];
        acc = bf2f(xws[(size_t)wv * HID + c]);        // self-loop term
    }
    int j = beg;
    for (; j + 4 <= endp; j += 4) {
        int s0 = csr[j], s1 = csr[j + 1], s2 = csr[j + 2], s3 = csr[j + 3];
        acc += bf2f(xws[(size_t)s0 * HID + c]) + bf2f(xws[(size_t)s1 * HID + c])
             + bf2f(xws[(size_t)s2 * HID + c]) + bf2f(xws[(size_t)s3 * HID + c]);
    }
    for (; j < endp; ++j) acc += bf2f(xws[(size_t)csr[j] * HID + c]);
    float hv = active ? fmaxf(acc * di + b1[c], 0.f) : 0.f;
    hbuf[wave][c] = hv;
    __syncthreads();
    if (active && c < CLS) {
        float o = 0.f;
        const float* hr = hbuf[wave];
        #pragma unroll 8
        for (int k = 0; k < HID; ++k) o += hr[k] * W2[k * CLS + c];
        hws[(size_t)wv * CLS + c] = f2bf(o * di);
    }
}

// ---------- layer 2 gather fused with finalize ------------------------------
__global__ void gather2_fin_kernel(const int* __restrict__ rowptr,
                                   const ushort_t* __restrict__ csr,
                                   const ushort_t* __restrict__ hws,
                                   const float* __restrict__ dinv,
                                   const float* __restrict__ b2,
                                   float* __restrict__ xout, float* __restrict__ lsm,
                                   float* __restrict__ sm, ushort_t* __restrict__ xoutb,
                                   float* __restrict__ rnorm, int n) {
    int wv = (blockIdx.x * blockDim.x + threadIdx.x) >> 6;
    int c  = threadIdx.x & 63;
    if (wv >= n) return;
    int beg = rowptr[wv], endp = rowptr[wv + 1];
    float acc = 0.f;
    if (c < CLS) acc = bf2f(hws[(size_t)wv * CLS + c]);   // self-loop term
    int j = beg;
    for (; j + 4 <= endp; j += 4) {
        int s0 = csr[j], s1 = csr[j + 1], s2 = csr[j + 2], s3 = csr[j + 3];
        if (c < CLS)
            acc += bf2f(hws[(size_t)s0 * CLS + c]) + bf2f(hws[(size_t)s1 * CLS + c])
                 + bf2f(hws[(size_t)s2 * CLS + c]) + bf2f(hws[(size_t)s3 * CLS + c]);
    }
    for (; j < endp; ++j) {
        int s = csr[j];
        if (c < CLS) acc += bf2f(hws[(size_t)s * CLS + c]);
    }
    float raw = 0.f;
    if (c < CLS) raw = acc * dinv[wv] + b2[c];
    float m = (c < CLS) ? raw : -3.0e38f;
    #pragma unroll
    for (int o = 32; o > 0; o >>= 1) m = fmaxf(m, __shfl_xor(m, o));
    float ex = (c < CLS) ? __expf(raw - m) : 0.f;
    float ssum = ex;
    #pragma unroll
    for (int o = 32; o > 0; o >>= 1) ssum += __shfl_xor(ssum, o);
    float sq = (c < CLS) ? raw * raw : 0.f;
    #pragma unroll
    for (int o = 32; o > 0; o >>= 1) sq += __shfl_xor(sq, o);
    size_t base = (size_t)wv * CLS + c;
    if (c < CLS) {
        xout[base]  = raw;
        float lse = m + __logf(ssum);
        lsm[base]   = raw - lse;
        sm[base]    = ex / ssum;
        xoutb[base] = f2bf(raw);
    }
    if (c == 0) rnorm[wv] = 1.0f / fmaxf(sqrtf(sq), EPS);
}

// ------------- per-edge cosine dissimilarity + gnn_edge ---------------------
__global__ void edge_kernel(const ushort_t* __restrict__ src, const ushort_t* __restrict__ dst,
                            const float* __restrict__ ew, const ushort_t* __restrict__ xoutb,
                            const float* __restrict__ rnorm,
                            float* __restrict__ cos_out, float* __restrict__ gnn_out, int E) {
    int e = blockIdx.x * blockDim.x + threadIdx.x;
    if (e >= E) return;
    int s = src[e], d = dst[e];
    const uint2* a = (const uint2*)(xoutb + (size_t)s * CLS);
    const uint2* b = (const uint2*)(xoutb + (size_t)d * CLS);
    float dot = 0.f;
    #pragma unroll
    for (int i = 0; i < CLS / 4; ++i) {   // 10 x uint2 = 40 bf16 per row
        uint2 av = a[i], bv = b[i];
        dot += blo(av.x) * blo(bv.x) + bhi(av.x) * bhi(bv.x)
             + blo(av.y) * blo(bv.y) + bhi(av.y) * bhi(bv.y);
    }
    cos_out[e] = 1.0f - dot * rnorm[s] * rnorm[d];
    gnn_out[e] = (ew[e] > 0.5f) ? 1.0f : -1.0f;
}

// ---------------------------------------------------------------------------
extern "C" void kernel_launch(void* const* d_in, const int* in_sizes, int n_in,
                              void* d_out, int out_size, void* d_ws, size_t ws_size,
                              hipStream_t stream) {
    const float* x   = (const float*)d_in[0];
    const void*  ei  = d_in[1];
    const float* ew  = (const float*)d_in[2];
    const float* W1  = (const float*)d_in[3];
    const float* b1  = (const float*)d_in[4];
    const float* W2  = (const float*)d_in[5];
    const float* b2  = (const float*)d_in[6];

    const int n = in_sizes[0] / F_IN;        // 50000
    const int E = in_sizes[2];               // 1600000

    // output segments (return order)
    float* lsm  = (float*)d_out;                                   // [n*CLS]
    float* xout = lsm + (size_t)n * CLS;                           // [n*CLS]
    float* cosO = xout + (size_t)n * CLS;                          // [E]
    float* gnnO = cosO + E;                                        // [E]
    float* smO  = gnnO + E;                                        // [n*CLS]

    // workspace layout (256B aligned)
    char* w = (char*)d_ws;
    auto alloc = [&](size_t bytes) {
        char* p = w;
        w += (bytes + 255) & ~(size_t)255;
        return p;
    };
    ushort_t* src16  = (ushort_t*)alloc((size_t)E * 2);
    ushort_t* dst16  = (ushort_t*)alloc((size_t)E * 2);
    ushort_t* csr16  = (ushort_t*)alloc((size_t)E * 2);
    int*      deg    = (int*)     alloc((size_t)n * 4);
    int*      rowptr = (int*)     alloc(((size_t)n + 1) * 4);
    int*      cursor = (int*)     alloc((size_t)n * 4);
    float*    dinv   = (float*)   alloc((size_t)n * 4);
    ushort_t* xws    = (ushort_t*)alloc((size_t)n * HID * 2);
    ushort_t* hws    = (ushort_t*)alloc((size_t)n * CLS * 2);
    ushort_t* xoutb  = (ushort_t*)alloc((size_t)n * CLS * 2);
    float*    rnorm  = (float*)   alloc((size_t)n * 4);
    int*      flag   = (int*)     alloc(64);

    detect_kernel<<<1, 64, 0, stream>>>((const int*)ei, flag);
    init_deg_kernel<<<(n + 255) / 256, 256, 0, stream>>>(deg, n);
    convert_kernel<<<(E + 255) / 256, 256, 0, stream>>>(ei, flag, src16, dst16, deg, E);
    dinv_kernel<<<(n + 255) / 256, 256, 0, stream>>>(deg, dinv, n);
    scan_kernel<<<1, 1024, 0, stream>>>(deg, rowptr, cursor, n);
    fill_kernel<<<(E + 255) / 256, 256, 0, stream>>>(src16, dst16, cursor, csr16, E);
    gemm1_kernel<<<(n + 15) / 16, 256, 0, stream>>>(x, W1, dinv, xws, n);
    gather1_gemm2_kernel<<<((size_t)n * 64 + 255) / 256, 256, 0, stream>>>(rowptr, csr16, xws, dinv,
                                                                           b1, W2, hws, n);
    gather2_fin_kernel<<<((size_t)n * 64 + 255) / 256, 256, 0, stream>>>(rowptr, csr16, hws, dinv, b2,
                                                                         xout, lsm, smO, xoutb, rnorm, n);
    edge_kernel<<<(E + 255) / 256, 256, 0, stream>>>(src16, dst16, ew, xoutb, rnorm, cosO, gnnO, E);
}